// Round 5
// baseline (125.061 us; speedup 1.0000x reference)
//
#include <hip/hip_runtime.h>

#define KTAPS 10
#define SKIP  2
#define TRANS 100
#define PAD   ((KTAPS - 1) * SKIP)   // 18
#define NFEAT 231                    // 1 + 10 + 220
#define NIN   4096
#define NT    (NIN - TRANS)          // 3996
#define NROWS 32                     // 8*4
#define TT    40                     // timesteps per block (one wave); 40%4==0
#define NTILES ((NT + TT - 1) / TT)  // 100; last tile = 36 steps (36%4==0)

// One WAVE per block. Lane = timestep. The wave computes its 40x231 feature
// slab into private LDS, then streams it to global as one long unbarriered
// run of ds_read_b128 -> global_store_dwordx4. No __syncthreads after any
// store is issued => no vmcnt(0) drain; waves exit with stores in flight.
__global__ __launch_bounds__(64) void nvar_kernel(const float* __restrict__ X,
                                                  float* __restrict__ out) {
    __shared__ __align__(16) float feat[TT * NFEAT];  // 36,960 B -> 4 blocks/CU

    const int tile = blockIdx.x;
    const int row  = blockIdx.y;
    const int t0   = tile * TT;
    const int tcount = min(TT, NT - t0);              // 40 or 36

    const int tl = threadIdx.x;                       // 0..63; lanes >= TT idle in compute
    const float* xrow = X + (size_t)row * NIN;

    if (tl < TT) {
        int tg = t0 + tl;
        if (tg >= NT) tg = NT - 1;                    // tail clamp; rows >= tcount never copied

        // lin_k(t) = X[row, t + 82 + 2k]; max index 4095 -> always in-bounds.
        float tap[KTAPS];
#pragma unroll
        for (int k = 0; k < KTAPS; ++k)
            tap[k] = xrow[tg + (TRANS - PAD) + 2 * k];

        // Row layout == output layout (stride 231). Per-lane row base: bank =
        // (7*tl + f) % 32 -> lanes of the wave hit distinct banks (<=2-way, free).
        float* frow = feat + tl * NFEAT;
        frow[0] = 1.0f;
#pragma unroll
        for (int k = 0; k < KTAPS; ++k)
            frow[1 + k] = tap[k];

        // Monomials, lex order of combinations_with_replacement(range(10),3),
        // fully unrolled: every index/offset is a compile-time constant.
        int fb = 1 + KTAPS;
#pragma unroll
        for (int i = 0; i < KTAPS; ++i) {
#pragma unroll
            for (int j = i; j < KTAPS; ++j) {
                const float pij = tap[i] * tap[j];
#pragma unroll
                for (int l = j; l < KTAPS; ++l)
                    frow[fb + (l - j)] = pij * tap[l];
                fb += KTAPS - j;
            }
        }
    }

    // Single wave: ds ops are wave-order guaranteed; this barrier is belt-and-
    // braces for compiler ordering and costs ~nothing (no stores in flight yet).
    __syncthreads();

    // Flat streaming copy: LDS slab is byte-identical to the output slab.
    // tcount*NFEAT % 4 == 0; global base (row*3996 + 40*tile)*231 % 4 == 0.
    const int total4 = (tcount * NFEAT) >> 2;         // 2310 or 2079
    float4* __restrict__ o4 =
        reinterpret_cast<float4*>(out + ((size_t)row * NT + t0) * NFEAT);
    const float4* s4 = reinterpret_cast<const float4*>(feat);
#pragma unroll 4
    for (int i = threadIdx.x; i < total4; i += 64)
        o4[i] = s4[i];
}

extern "C" void kernel_launch(void* const* d_in, const int* in_sizes, int n_in,
                              void* d_out, int out_size, void* d_ws, size_t ws_size,
                              hipStream_t stream) {
    const float* X = (const float*)d_in[0];
    float* out = (float*)d_out;
    dim3 grid(NTILES, NROWS);                         // 100 x 32 = 3200 one-wave blocks
    nvar_kernel<<<grid, 64, 0, stream>>>(X, out);
}